// Round 2
// baseline (818.742 us; speedup 1.0000x reference)
//
#include <hip/hip_runtime.h>
#include <math.h>

// B=16384 (M), C=4096 (N), D=256.
// logits[b,c] = -0.5*(sum_d (z-mu)^2*e^{-lv} + sum_d lv + D*log 2pi) - log C
// GEMM form (K=1536, f16 hi/lo split -> ~22-bit product precision):
//   A  = [z^2 , z]             (K=512, per row b)
//   W  = [-0.5*iv , mu*iv]     (K=512, per class c; -0.5 folded in)
//   quadterm = A_hi.W_hi + A_hi.W_lo + A_lo.W_hi   (drop lo*lo)
//   logits = GEMM(Atil, Wtil) + Kc[c]

constexpr int M = 16384;
constexpr int N = 4096;
constexpr int DD = 256;
constexpr int K = 1536;
constexpr int BM = 256, BN = 256, BK = 64;
constexpr int NT = K / BK;   // 24 K-tiles

typedef _Float16 half_t;
typedef __attribute__((ext_vector_type(8))) _Float16 half8;
typedef __attribute__((ext_vector_type(4))) float floatx4;

#define GLOBAL_AS(p) ((const __attribute__((address_space(1))) void*)(p))
#define LDS_AS(p) ((__attribute__((address_space(3))) void*)(p))

__global__ __launch_bounds__(256) void prep_w_kernel(const float* __restrict__ mu,
                                                     const float* __restrict__ logvar,
                                                     half_t* __restrict__ Wt,
                                                     float* __restrict__ Kc) {
    const int c = blockIdx.x;
    const int d = threadIdx.x;
    const float lv = logvar[(size_t)c * DD + d];
    const float m  = mu[(size_t)c * DD + d];
    const float iv = __expf(-lv);
    const float w1 = -0.5f * iv;   // multiplies z^2
    const float w2 = m * iv;       // multiplies z   (-0.5 * -2 = +1)
    const half_t w1h = (half_t)w1;
    const half_t w1l = (half_t)(w1 - (float)w1h);
    const half_t w2h = (half_t)w2;
    const half_t w2l = (half_t)(w2 - (float)w2h);
    half_t* row = Wt + (size_t)c * K;
    row[d]        = w1h;   // pairs A_hi(z^2)
    row[256 + d]  = w2h;   // pairs A_hi(z)
    row[512 + d]  = w1l;   // pairs A_hi(z^2)
    row[768 + d]  = w2l;   // pairs A_hi(z)
    row[1024 + d] = w1h;   // pairs A_lo(z^2)
    row[1280 + d] = w2h;   // pairs A_lo(z)

    float s = m * m * iv + lv;
    #pragma unroll
    for (int off = 32; off > 0; off >>= 1) s += __shfl_down(s, off, 64);
    __shared__ float ls[4];
    const int lane = threadIdx.x & 63, wvi = threadIdx.x >> 6;
    if (lane == 0) ls[wvi] = s;
    __syncthreads();
    if (threadIdx.x == 0) {
        const float t = ls[0] + ls[1] + ls[2] + ls[3];
        // -0.5*sum - 0.5*256*log(2pi) - log(4096)
        Kc[c] = -0.5f * t - 235.24826450039618f - 8.31776616671934f;
    }
}

__global__ __launch_bounds__(256) void prep_a_kernel(const float* __restrict__ z,
                                                     half_t* __restrict__ At) {
    const int b = blockIdx.x;
    const int d = threadIdx.x;
    const float zv = z[(size_t)b * DD + d];
    const float z2 = zv * zv;
    const half_t z2h = (half_t)z2;
    const half_t z2l = (half_t)(z2 - (float)z2h);
    const half_t zh  = (half_t)zv;
    const half_t zl  = (half_t)(zv - (float)zh);
    half_t* row = At + (size_t)b * K;
    row[d]        = z2h;
    row[256 + d]  = zh;
    row[512 + d]  = z2h;
    row[768 + d]  = zh;
    row[1024 + d] = z2l;
    row[1280 + d] = zl;
}

// 256x256 tile, BK=64, 8 waves (2M x 4N), 512 threads, 128 KiB LDS (2 dbuf).
// Deep pipeline with counted vmcnt (T3+T4). Per tile t, 4 phases:
//   q0: read af(ks0,miquad0)+bf(ks0) [8 ds_read], stage A(t+1) half0 -> buf p^1
//   q1: read af(ks0,miquad1)+bf(ks1) [8],          stage A(t+1) half1 -> buf p^1
//   q2: read af(ks1,miquad0) [4],                  stage B(t+2) half0 -> buf p
//   q3: read af(ks1,miquad1) [4],                  stage B(t+2) half1 -> buf p
// B(t+2) into the live buffer is race-free: its last ds_read (bf ks1, issued
// q1) retires at q1's lgkmcnt(0), >=1 barrier before q2's staging issues.
// vmcnt(4) once per tile (q3) completes staging through tile t+1.
// NO sched_barrier(0) in the loop (m141: order-pinning costs ~40%); the LDS
// reads are compiler-visible, the explicit lgkmcnt(0) is the only fence.
// LDS rows are 64 f16 = 128 B; stored 16B-chunk = logical ^ (row&7), applied
// by pre-swizzling the global source (global_load_lds dest must stay linear).
__global__ __launch_bounds__(512, 2) void gemm_kernel(const half_t* __restrict__ At,
                                                      const half_t* __restrict__ Wt,
                                                      const float* __restrict__ Kc,
                                                      float* __restrict__ logits) {
    __shared__ half_t As[2][BM * BK];   // 64 KiB
    __shared__ half_t Bs[2][BN * BK];   // 64 KiB

    // XCD-chunked bijective swizzle: 1024 blocks, 8 XCDs; each XCD owns a
    // 2-wide column band (2 n-tiles x 64 m-tiles) so its Wt panels stay L2-hot.
    const int bid = blockIdx.x;
    const int xcd = bid & 7;
    const int lid = bid >> 3;
    const int bn0 = (xcd * 2 + (lid & 1)) * BN;
    const int bm0 = (lid >> 1) * BM;

    const int tid = threadIdx.x;
    const int lane = tid & 63;
    const int wvi = tid >> 6;           // 0..7
    const int wm = (wvi >> 2) * 128;    // 0 or 128
    const int wn = (wvi & 3) * 64;      // 0,64,128,192
    const int quad = lane >> 4;
    const int l15 = lane & 15;

    // staging: thread t, chunk-group j writes LDS bytes [j*8192 + t*16) ->
    // row = j*64 + (t>>3), stored chunk = t&7; logical chunk = stored ^ (row&7)
    const int r0 = tid >> 3;            // 0..63
    const int cl = ((tid & 7) ^ (r0 & 7)) * 8;   // element offset in row
    const char* gA = (const char*)(At + (size_t)(bm0 + r0) * K + cl);
    const char* gB = (const char*)(Wt + (size_t)(bn0 + r0) * K + cl);
    char* lA = (char*)As + tid * 16;
    char* lB = (char*)Bs + tid * 16;

    // stage half h (rows h*128..h*128+127) of a tile: 2 loads/thread
    #define STAGE(g, l, kt, h, buf)                                             \
        _Pragma("unroll")                                                       \
        for (int jj = 0; jj < 2; ++jj) {                                        \
            const int j = (h) * 2 + jj;                                         \
            __builtin_amdgcn_global_load_lds(                                   \
                GLOBAL_AS((g) + (size_t)(kt) * BK * 2 + (size_t)j * 64 * K * 2),\
                LDS_AS((l) + (buf) * 32768 + j * 8192), 16, 0, 0);              \
        }

    floatx4 acc[8][4] = {};

    // prologue: A(0), B(0), B(1); wait A(0)+B(0) (leave B(1)'s 4 in flight)
    STAGE(gA, lA, 0, 0, 0); STAGE(gA, lA, 0, 1, 0);
    STAGE(gB, lB, 0, 0, 0); STAGE(gB, lB, 0, 1, 0);
    STAGE(gB, lB, 1, 0, 1); STAGE(gB, lB, 1, 1, 1);
    asm volatile("s_waitcnt vmcnt(4)" ::: "memory");
    __builtin_amdgcn_s_barrier();

    for (int t = 0; t < NT; ++t) {
        const int p = t & 1;
        const half_t* Ab = &As[p][0];
        const half_t* Bb = &Bs[p][0];
        half8 bf0[4], bf1[4];
        #pragma unroll
        for (int q = 0; q < 4; ++q) {       // q = (ks<<1 ... ) : ks=q>>1, miquad=q&1
            const int ks = q >> 1;
            const int mq = q & 1;
            half8 af[4];
            #pragma unroll
            for (int i = 0; i < 4; ++i) {
                const int m = wm + (mq * 4 + i) * 16 + l15;
                const int c8 = (ks * 4 + quad) ^ (m & 7);
                af[i] = *(const half8*)(Ab + m * BK + c8 * 8);
            }
            if (q == 0) {                   // B frags for ks=0
                #pragma unroll
                for (int ni = 0; ni < 4; ++ni) {
                    const int n = wn + ni * 16 + l15;
                    const int c8 = quad ^ (n & 7);
                    bf0[ni] = *(const half8*)(Bb + n * BK + c8 * 8);
                }
            }
            if (q == 1) {                   // B frags for ks=1 (used q2/q3)
                #pragma unroll
                for (int ni = 0; ni < 4; ++ni) {
                    const int n = wn + ni * 16 + l15;
                    const int c8 = (4 + quad) ^ (n & 7);
                    bf1[ni] = *(const half8*)(Bb + n * BK + c8 * 8);
                }
            }
            // staging ring
            if (q < 2) {
                if (t + 1 < NT) STAGE(gA, lA, t + 1, q, p ^ 1);
            } else {
                if (t + 2 < NT) STAGE(gB, lB, t + 2, q - 2, p);
            }
            __builtin_amdgcn_s_barrier();
            asm volatile("s_waitcnt lgkmcnt(0)" ::: "memory");
            __builtin_amdgcn_s_setprio(1);
            #pragma unroll
            for (int i = 0; i < 4; ++i)
                #pragma unroll
                for (int ni = 0; ni < 4; ++ni)
                    acc[mq * 4 + i][ni] = __builtin_amdgcn_mfma_f32_16x16x32_f16(
                        af[i], (ks == 0) ? bf0[ni] : bf1[ni], acc[mq * 4 + i][ni], 0, 0, 0);
            __builtin_amdgcn_s_setprio(0);
            if (q == 3) {
                if (t + 2 < NT) {
                    asm volatile("s_waitcnt vmcnt(4)" ::: "memory");  // through tile t+1
                } else if (t + 1 < NT) {
                    asm volatile("s_waitcnt vmcnt(0)" ::: "memory");  // drain for last tile
                }
            }
            __builtin_amdgcn_s_barrier();
        }
    }

    // epilogue: C/D layout col=lane&15, row=quad*4+reg (m89-verified)
    float kc[4];
    #pragma unroll
    for (int ni = 0; ni < 4; ++ni) kc[ni] = Kc[bn0 + wn + ni * 16 + l15];
    #pragma unroll
    for (int mi = 0; mi < 8; ++mi) {
        const int row0 = bm0 + wm + mi * 16 + quad * 4;
        #pragma unroll
        for (int ni = 0; ni < 4; ++ni) {
            const int col = bn0 + wn + ni * 16 + l15;
            float* outp = logits + (size_t)row0 * N + col;
            #pragma unroll
            for (int r = 0; r < 4; ++r)
                outp[(size_t)r * N] = acc[mi][ni][r] + kc[ni];
        }
    }
    #undef STAGE
}

// one block per row: load 4096 logits (4 float4/thread), block max+argmax,
// sum of exp, write probs + predicted class (as float).
__global__ __launch_bounds__(256) void softmax_kernel(const float* __restrict__ logits,
                                                      float* __restrict__ probs,
                                                      float* __restrict__ pred) {
    const int row = blockIdx.x;
    const int tid = threadIdx.x;
    const int lane = tid & 63, wvi = tid >> 6;
    const float4* lrow = (const float4*)(logits + (size_t)row * N);
    float4 v[4];
    float vmax = -INFINITY;
    int vidx = 0;
    #pragma unroll
    for (int j = 0; j < 4; ++j) {
        v[j] = lrow[j * 256 + tid];
        const int base = (j * 256 + tid) * 4;
        if (v[j].x > vmax) { vmax = v[j].x; vidx = base; }
        if (v[j].y > vmax) { vmax = v[j].y; vidx = base + 1; }
        if (v[j].z > vmax) { vmax = v[j].z; vidx = base + 2; }
        if (v[j].w > vmax) { vmax = v[j].w; vidx = base + 3; }
    }
    #pragma unroll
    for (int off = 32; off > 0; off >>= 1) {
        const float ov = __shfl_down(vmax, off, 64);
        const int oi = __shfl_down(vidx, off, 64);
        if (ov > vmax || (ov == vmax && oi < vidx)) { vmax = ov; vidx = oi; }
    }
    __shared__ float smax[4];
    __shared__ int sidx[4];
    __shared__ float ssum[4];
    if (lane == 0) { smax[wvi] = vmax; sidx[wvi] = vidx; }
    __syncthreads();
    float rmax = smax[0];
    int ridx = sidx[0];
    #pragma unroll
    for (int i = 1; i < 4; ++i)
        if (smax[i] > rmax || (smax[i] == rmax && sidx[i] < ridx)) { rmax = smax[i]; ridx = sidx[i]; }

    float s = 0.f;
    float4 e[4];
    #pragma unroll
    for (int j = 0; j < 4; ++j) {
        e[j].x = __expf(v[j].x - rmax);
        e[j].y = __expf(v[j].y - rmax);
        e[j].z = __expf(v[j].z - rmax);
        e[j].w = __expf(v[j].w - rmax);
        s += e[j].x + e[j].y + e[j].z + e[j].w;
    }
    #pragma unroll
    for (int off = 32; off > 0; off >>= 1) s += __shfl_down(s, off, 64);
    if (lane == 0) ssum[wvi] = s;
    __syncthreads();
    const float inv = 1.f / (ssum[0] + ssum[1] + ssum[2] + ssum[3]);
    float4* prow = (float4*)(probs + (size_t)row * N);
    #pragma unroll
    for (int j = 0; j < 4; ++j) {
        float4 o;
        o.x = e[j].x * inv; o.y = e[j].y * inv; o.z = e[j].z * inv; o.w = e[j].w * inv;
        prow[j * 256 + tid] = o;
    }
    if (tid == 0) pred[row] = (float)ridx;
}

extern "C" void kernel_launch(void* const* d_in, const int* in_sizes, int n_in,
                              void* d_out, int out_size, void* d_ws, size_t ws_size,
                              hipStream_t stream) {
    const float* z      = (const float*)d_in[0];
    const float* mu     = (const float*)d_in[1];
    const float* logvar = (const float*)d_in[2];
    float* out    = (float*)d_out;
    float* logits = out;                          // [M*N]
    float* probs  = out + (size_t)M * N;          // [M*N]
    float* pred   = out + (size_t)2 * M * N;      // [M]

    // Scratch (63 MB) carved from the probs region (268 MB): probs is written
    // only by the final softmax kernel, after the GEMM has consumed At/Wt/Kc.
    char* scratch = (char*)probs;
    half_t* At = (half_t*)scratch;                                          // M*K*2 = 50,331,648 B
    half_t* Wt = (half_t*)(scratch + (size_t)M * K * 2);                    // N*K*2 = 12,582,912 B
    float*  Kc = (float*)(scratch + (size_t)M * K * 2 + (size_t)N * K * 2); // 16 KB

    prep_w_kernel<<<N, 256, 0, stream>>>(mu, logvar, Wt, Kc);
    prep_a_kernel<<<M, 256, 0, stream>>>(z, At);
    gemm_kernel<<<dim3(N / BN * M / BM), 512, 0, stream>>>(At, Wt, Kc, logits);
    softmax_kernel<<<M, 256, 0, stream>>>(logits, probs, pred);
}

// Round 3
// 780.823 us; speedup vs baseline: 1.0486x; 1.0486x over previous
//
#include <hip/hip_runtime.h>
#include <math.h>

// B=16384 (M), C=4096 (N), D=256.
// logits[b,c] = -0.5*(sum_d (z-mu)^2*e^{-lv} + sum_d lv + D*log 2pi) - log C
// GEMM form (K=1536, f16 hi/lo split -> ~22-bit product precision):
//   A  = [z^2 , z]             (K=512, per row b)
//   W  = [-0.5*iv , mu*iv]     (K=512, per class c; -0.5 folded in)
//   quadterm = A_hi.W_hi + A_hi.W_lo + A_lo.W_hi   (drop lo*lo)
//   logits = GEMM(Atil, Wtil) + Kc[c]

constexpr int M = 16384;
constexpr int N = 4096;
constexpr int DD = 256;
constexpr int K = 1536;
constexpr int BM = 128, BN = 128, BK = 64;

typedef _Float16 half_t;
typedef __attribute__((ext_vector_type(8))) _Float16 half8;
typedef __attribute__((ext_vector_type(16))) float floatx16;

#define GLOBAL_AS(p) ((const __attribute__((address_space(1))) void*)(p))
#define LDS_AS(p) ((__attribute__((address_space(3))) void*)(p))

__global__ __launch_bounds__(256) void prep_w_kernel(const float* __restrict__ mu,
                                                     const float* __restrict__ logvar,
                                                     half_t* __restrict__ Wt,
                                                     float* __restrict__ Kc) {
    const int c = blockIdx.x;
    const int d = threadIdx.x;
    const float lv = logvar[(size_t)c * DD + d];
    const float m  = mu[(size_t)c * DD + d];
    const float iv = __expf(-lv);
    const float w1 = -0.5f * iv;   // multiplies z^2
    const float w2 = m * iv;       // multiplies z   (-0.5 * -2 = +1)
    const half_t w1h = (half_t)w1;
    const half_t w1l = (half_t)(w1 - (float)w1h);
    const half_t w2h = (half_t)w2;
    const half_t w2l = (half_t)(w2 - (float)w2h);
    half_t* row = Wt + (size_t)c * K;
    row[d]        = w1h;   // pairs A_hi(z^2)
    row[256 + d]  = w2h;   // pairs A_hi(z)
    row[512 + d]  = w1l;   // pairs A_hi(z^2)
    row[768 + d]  = w2l;   // pairs A_hi(z)
    row[1024 + d] = w1h;   // pairs A_lo(z^2)
    row[1280 + d] = w2h;   // pairs A_lo(z)

    float s = m * m * iv + lv;
    #pragma unroll
    for (int off = 32; off > 0; off >>= 1) s += __shfl_down(s, off, 64);
    __shared__ float ls[4];
    const int lane = threadIdx.x & 63, wvi = threadIdx.x >> 6;
    if (lane == 0) ls[wvi] = s;
    __syncthreads();
    if (threadIdx.x == 0) {
        const float t = ls[0] + ls[1] + ls[2] + ls[3];
        // -0.5*sum - 0.5*256*log(2pi) - log(4096)
        Kc[c] = -0.5f * t - 235.24826450039618f - 8.31776616671934f;
    }
}

__global__ __launch_bounds__(256) void prep_a_kernel(const float* __restrict__ z,
                                                     half_t* __restrict__ At) {
    const int b = blockIdx.x;
    const int d = threadIdx.x;
    const float zv = z[(size_t)b * DD + d];
    const float z2 = zv * zv;
    const half_t z2h = (half_t)z2;
    const half_t z2l = (half_t)(z2 - (float)z2h);
    const half_t zh  = (half_t)zv;
    const half_t zl  = (half_t)(zv - (float)zh);
    half_t* row = At + (size_t)b * K;
    row[d]        = z2h;
    row[256 + d]  = zh;
    row[512 + d]  = z2h;
    row[768 + d]  = zh;
    row[1024 + d] = z2l;
    row[1280 + d] = zl;
}

// Round-0 structure (128x128 tile, BK=64, 4 waves, single-buffered LDS,
// global_load_lds width=16, ~3 blocks/CU implicit overlap) with ONE change:
// MFMA shape 16x16x32 -> 32x32x16. Per K-tile per wave: ds_read_b128 count
// 24 -> 16 (-33%, the binding LDS-issue pipe) and MFMA cycles -16%
// (8.07cy/32k-FLOP vs 4.85/16k). Wave tile 64x64 = 2x2 frags of 32x32,
// acc = 2x2 floatx16 = 64 VGPR (same as before).
// Fragment mapping (derived from the verified 16x16 pattern):
//   A/B operand: row = lane&31, k-octet = lane>>5 (8 f16 per lane)
//   C/D: col = lane&31, row = (reg&3) + 8*(reg>>2) + 4*(lane>>5)  [m74/m101]
// LDS rows are 64 f16 = 128 B; stored 16B-chunk = logical ^ (row&7), applied
// by pre-swizzling the global source (global_load_lds dest must stay linear).
__global__ __launch_bounds__(256) void gemm_kernel(const half_t* __restrict__ At,
                                                   const half_t* __restrict__ Wt,
                                                   const float* __restrict__ Kc,
                                                   float* __restrict__ logits) {
    __shared__ half_t As[BM * BK];
    __shared__ half_t Bs[BN * BK];

    const int bn0 = blockIdx.x * BN;
    const int bm0 = blockIdx.y * BM;
    const int tid = threadIdx.x;
    const int lane = tid & 63;
    const int wvi = tid >> 6;
    const int wm = (wvi & 1) * 64;
    const int wn = (wvi >> 1) * 64;
    const int l31 = lane & 31;
    const int lhi = lane >> 5;          // 0 or 1: k-octet within a 16-k step

    // staging: thread t, call i writes LDS bytes [t*16 + i*4096): row
    // r=(t>>3)+i*32, stored chunk s=t&7, logical chunk = s ^ (r&7)
    const int r0 = tid >> 3;
    const int cl = ((tid & 7) ^ (r0 & 7)) * 8;   // element offset within row
    const char* gA = (const char*)(At + (size_t)(bm0 + r0) * K + cl);
    const char* gB = (const char*)(Wt + (size_t)(bn0 + r0) * K + cl);
    char* lA = (char*)As + tid * 16;
    char* lB = (char*)Bs + tid * 16;

    floatx16 acc[2][2] = {};

    for (int kt = 0; kt < K / BK; ++kt) {
        const size_t kb = (size_t)kt * BK * 2;  // byte offset along K
        #pragma unroll
        for (int i = 0; i < 4; ++i) {
            __builtin_amdgcn_global_load_lds(GLOBAL_AS(gA + kb + (size_t)i * 32 * K * 2),
                                             LDS_AS(lA + i * 4096), 16, 0, 0);
            __builtin_amdgcn_global_load_lds(GLOBAL_AS(gB + kb + (size_t)i * 32 * K * 2),
                                             LDS_AS(lB + i * 4096), 16, 0, 0);
        }
        __syncthreads();
        #pragma unroll
        for (int kp = 0; kp < 2; ++kp) {        // two 32-k halves, 2 insts each
            half8 af[2][2], bf[2][2];           // [mi|ni][j], kk = kp*2+j
            #pragma unroll
            for (int mi = 0; mi < 2; ++mi)
                #pragma unroll
                for (int j = 0; j < 2; ++j) {
                    const int m = wm + mi * 32 + l31;
                    const int o = (kp * 2 + j) * 2 + lhi;   // logical octet 0..7
                    const int c8 = o ^ (m & 7);             // stored position
                    af[mi][j] = *(const half8*)(As + m * BK + c8 * 8);
                }
            #pragma unroll
            for (int ni = 0; ni < 2; ++ni)
                #pragma unroll
                for (int j = 0; j < 2; ++j) {
                    const int n = wn + ni * 32 + l31;
                    const int o = (kp * 2 + j) * 2 + lhi;
                    const int c8 = o ^ (n & 7);
                    bf[ni][j] = *(const half8*)(Bs + n * BK + c8 * 8);
                }
            #pragma unroll
            for (int j = 0; j < 2; ++j)
                #pragma unroll
                for (int mi = 0; mi < 2; ++mi)
                    #pragma unroll
                    for (int ni = 0; ni < 2; ++ni)
                        acc[mi][ni] = __builtin_amdgcn_mfma_f32_32x32x16_f16(
                            af[mi][j], bf[ni][j], acc[mi][ni], 0, 0, 0);
        }
        __syncthreads();
    }

    // epilogue: C/D col=lane&31, row=(reg&3)+8*(reg>>2)+4*(lane>>5)
    float kc[2];
    #pragma unroll
    for (int ni = 0; ni < 2; ++ni) kc[ni] = Kc[bn0 + wn + ni * 32 + l31];
    #pragma unroll
    for (int mi = 0; mi < 2; ++mi) {
        const int rbase = bm0 + wm + mi * 32 + 4 * lhi;
        #pragma unroll
        for (int ni = 0; ni < 2; ++ni) {
            const int col = bn0 + wn + ni * 32 + l31;
            #pragma unroll
            for (int g = 0; g < 4; ++g) {
                float* outp = logits + (size_t)(rbase + g * 8) * N + col;
                #pragma unroll
                for (int r = 0; r < 4; ++r)
                    outp[(size_t)r * N] = acc[mi][ni][g * 4 + r] + kc[ni];
            }
        }
    }
}

// one block per row: load 4096 logits (4 float4/thread), block max+argmax,
// sum of exp, write probs + predicted class (as float).
__global__ __launch_bounds__(256) void softmax_kernel(const float* __restrict__ logits,
                                                      float* __restrict__ probs,
                                                      float* __restrict__ pred) {
    const int row = blockIdx.x;
    const int tid = threadIdx.x;
    const int lane = tid & 63, wvi = tid >> 6;
    const float4* lrow = (const float4*)(logits + (size_t)row * N);
    float4 v[4];
    float vmax = -INFINITY;
    int vidx = 0;
    #pragma unroll
    for (int j = 0; j < 4; ++j) {
        v[j] = lrow[j * 256 + tid];
        const int base = (j * 256 + tid) * 4;
        if (v[j].x > vmax) { vmax = v[j].x; vidx = base; }
        if (v[j].y > vmax) { vmax = v[j].y; vidx = base + 1; }
        if (v[j].z > vmax) { vmax = v[j].z; vidx = base + 2; }
        if (v[j].w > vmax) { vmax = v[j].w; vidx = base + 3; }
    }
    #pragma unroll
    for (int off = 32; off > 0; off >>= 1) {
        const float ov = __shfl_down(vmax, off, 64);
        const int oi = __shfl_down(vidx, off, 64);
        if (ov > vmax || (ov == vmax && oi < vidx)) { vmax = ov; vidx = oi; }
    }
    __shared__ float smax[4];
    __shared__ int sidx[4];
    __shared__ float ssum[4];
    if (lane == 0) { smax[wvi] = vmax; sidx[wvi] = vidx; }
    __syncthreads();
    float rmax = smax[0];
    int ridx = sidx[0];
    #pragma unroll
    for (int i = 1; i < 4; ++i)
        if (smax[i] > rmax || (smax[i] == rmax && sidx[i] < ridx)) { rmax = smax[i]; ridx = sidx[i]; }

    float s = 0.f;
    float4 e[4];
    #pragma unroll
    for (int j = 0; j < 4; ++j) {
        e[j].x = __expf(v[j].x - rmax);
        e[j].y = __expf(v[j].y - rmax);
        e[j].z = __expf(v[j].z - rmax);
        e[j].w = __expf(v[j].w - rmax);
        s += e[j].x + e[j].y + e[j].z + e[j].w;
    }
    #pragma unroll
    for (int off = 32; off > 0; off >>= 1) s += __shfl_down(s, off, 64);
    if (lane == 0) ssum[wvi] = s;
    __syncthreads();
    const float inv = 1.f / (ssum[0] + ssum[1] + ssum[2] + ssum[3]);
    float4* prow = (float4*)(probs + (size_t)row * N);
    #pragma unroll
    for (int j = 0; j < 4; ++j) {
        float4 o;
        o.x = e[j].x * inv; o.y = e[j].y * inv; o.z = e[j].z * inv; o.w = e[j].w * inv;
        prow[j * 256 + tid] = o;
    }
    if (tid == 0) pred[row] = (float)ridx;
}

extern "C" void kernel_launch(void* const* d_in, const int* in_sizes, int n_in,
                              void* d_out, int out_size, void* d_ws, size_t ws_size,
                              hipStream_t stream) {
    const float* z      = (const float*)d_in[0];
    const float* mu     = (const float*)d_in[1];
    const float* logvar = (const float*)d_in[2];
    float* out    = (float*)d_out;
    float* logits = out;                          // [M*N]
    float* probs  = out + (size_t)M * N;          // [M*N]
    float* pred   = out + (size_t)2 * M * N;      // [M]

    // Scratch (63 MB) carved from the probs region (268 MB): probs is written
    // only by the final softmax kernel, after the GEMM has consumed At/Wt/Kc.
    char* scratch = (char*)probs;
    half_t* At = (half_t*)scratch;                                          // M*K*2 = 50,331,648 B
    half_t* Wt = (half_t*)(scratch + (size_t)M * K * 2);                    // N*K*2 = 12,582,912 B
    float*  Kc = (float*)(scratch + (size_t)M * K * 2 + (size_t)N * K * 2); // 16 KB

    prep_w_kernel<<<N, 256, 0, stream>>>(mu, logvar, Wt, Kc);
    prep_a_kernel<<<M, 256, 0, stream>>>(z, At);
    gemm_kernel<<<dim3(N / BN, M / BM), 256, 0, stream>>>(At, Wt, Kc, logits);
    softmax_kernel<<<M, 256, 0, stream>>>(logits, probs, pred);
}